// Round 4
// baseline (715.877 us; speedup 1.0000x reference)
//
#include <hip/hip_runtime.h>

// SGC forward via device-built CSR + quarter-wave float4 gather, zero-LDS GEMMs.
//   dinv[i] = rsqrt(indeg[i] + 1)
//   prop(x)[d] = dinv[d] * ( sum_{(s,d)} dinv[s]*x[s] + dinv[d]*x[d] )
//   h1s = dinv .* relu(prop(x) @ W1^T + b1)        (stored pre-scaled)
//   prop2[d] = dinv[d] * ( sum h1s[s] + h1s[d] )   (pure adds)
//   out = relu(prop2 @ W2^T + b2) @ W3^T + b3
// GEMMs: weight row per lane in VGPRs; input broadcast via v_readlane (no LDS).

#define F 64
#define C 16
#define SCAN_B 1024

__device__ __forceinline__ float rl(float v, int lane) {
    return __uint_as_float(__builtin_amdgcn_readlane(__float_as_uint(v), lane));
}

// ---- degree histogram (int atomics), 4 edges/thread ----
__global__ void deg_kernel(const int* __restrict__ dst, int* __restrict__ deg, int E) {
    int i = (blockIdx.x * blockDim.x + threadIdx.x) * 4;
    if (i + 4 <= E) {
        int4 d = *(const int4*)(dst + i);
        atomicAdd(&deg[d.x], 1); atomicAdd(&deg[d.y], 1);
        atomicAdd(&deg[d.z], 1); atomicAdd(&deg[d.w], 1);
    } else {
        for (int k = i; k < E; ++k) atomicAdd(&deg[dst[k]], 1);
    }
}

// ---- exclusive scan of deg -> rowptr (3 kernels) ----
__global__ __launch_bounds__(256) void scan1_kernel(const int* __restrict__ deg,
                                                    int* __restrict__ part,
                                                    int* __restrict__ bsum, int n) {
    __shared__ int ts[256];
    int b = blockIdx.x, t = threadIdx.x;
    int base = b * SCAN_B + t * 4;
    int v[4], sum = 0;
#pragma unroll
    for (int k = 0; k < 4; ++k) { int i = base + k; v[k] = (i < n) ? deg[i] : 0; sum += v[k]; }
    ts[t] = sum;
    __syncthreads();
    for (int off = 1; off < 256; off <<= 1) {
        int add = (t >= off) ? ts[t - off] : 0;
        __syncthreads();
        ts[t] += add;
        __syncthreads();
    }
    int run = ts[t] - sum;
#pragma unroll
    for (int k = 0; k < 4; ++k) { int i = base + k; if (i < n) part[i] = run; run += v[k]; }
    if (t == 255) bsum[b] = ts[255];
}

__global__ __launch_bounds__(256) void scan2_kernel(int* __restrict__ bsum, int nb) {
    __shared__ int ts[256];
    int t = threadIdx.x;
    int v = (t < nb) ? bsum[t] : 0;
    ts[t] = v;
    __syncthreads();
    for (int off = 1; off < 256; off <<= 1) {
        int add = (t >= off) ? ts[t - off] : 0;
        __syncthreads();
        ts[t] += add;
        __syncthreads();
    }
    if (t < nb) bsum[t] = ts[t] - v;
}

// rowptr/cursor/dinv in one pass
__global__ void scan3_kernel(const int* __restrict__ part, const int* __restrict__ bsum,
                             const int* __restrict__ deg, int* __restrict__ rowptr,
                             int* __restrict__ cursor, float* __restrict__ dinv,
                             int n, int E) {
    int i = blockIdx.x * blockDim.x + threadIdx.x;
    if (i < n) {
        int r = part[i] + bsum[i / SCAN_B];
        rowptr[i] = r;
        cursor[i] = r;
        dinv[i] = rsqrtf((float)deg[i] + 1.0f);
    }
    if (i == 0) rowptr[n] = E;
}

// ---- bucket fill, 4 edges/thread ----
__global__ void fill_kernel(const int* __restrict__ src, const int* __restrict__ dst,
                            int* __restrict__ cursor, int* __restrict__ csr_src, int E) {
    int i = (blockIdx.x * blockDim.x + threadIdx.x) * 4;
    if (i + 4 <= E) {
        int4 s = *(const int4*)(src + i);
        int4 d = *(const int4*)(dst + i);
        int p0 = atomicAdd(&cursor[d.x], 1); csr_src[p0] = s.x;
        int p1 = atomicAdd(&cursor[d.y], 1); csr_src[p1] = s.y;
        int p2 = atomicAdd(&cursor[d.z], 1); csr_src[p2] = s.z;
        int p3 = atomicAdd(&cursor[d.w], 1); csr_src[p3] = s.w;
    } else {
        for (int k = i; k < E; ++k) {
            int pos = atomicAdd(&cursor[dst[k]], 1);
            csr_src[pos] = src[k];
        }
    }
}

// ---- layer 1: gather (dinv[s] fma) + lin1 + relu, store pre-scaled ----
__global__ __launch_bounds__(256, 4) void prop_lin1_kernel(
    const float4* __restrict__ x4, const int* __restrict__ rowptr,
    const int* __restrict__ csr_src, const float* __restrict__ dinv,
    const float* __restrict__ W1, const float* __restrict__ b1,
    float* __restrict__ h1s, int n) {
    int tid = threadIdx.x;
    int lane = tid & 63;
    int q = lane >> 4, m = lane & 15;
    int node = blockIdx.x * 4 + (tid >> 6);
    // per-lane weight row W1[lane][:] in registers (L1-hot, issued early)
    float4 w[16];
#pragma unroll
    for (int t = 0; t < 16; ++t) w[t] = *(const float4*)(W1 + (size_t)lane * F + 4 * t);
    float bias = b1[lane];
    if (node >= n) return;
    int beg = rowptr[node], end = rowptr[node + 1];
    float dd = dinv[node];
    float4 self = x4[(size_t)node * 16 + m];
    float4 a0 = make_float4(0.f, 0.f, 0.f, 0.f);
    float4 a1 = make_float4(0.f, 0.f, 0.f, 0.f);
    int p = beg;
    for (; p + 8 <= end; p += 8) {
        int s0 = csr_src[p + q];
        int s1 = csr_src[p + 4 + q];
        float d0 = dinv[s0], d1 = dinv[s1];
        float4 v0 = x4[(size_t)s0 * 16 + m];
        float4 v1 = x4[(size_t)s1 * 16 + m];
        a0.x = fmaf(d0, v0.x, a0.x); a0.y = fmaf(d0, v0.y, a0.y);
        a0.z = fmaf(d0, v0.z, a0.z); a0.w = fmaf(d0, v0.w, a0.w);
        a1.x = fmaf(d1, v1.x, a1.x); a1.y = fmaf(d1, v1.y, a1.y);
        a1.z = fmaf(d1, v1.z, a1.z); a1.w = fmaf(d1, v1.w, a1.w);
    }
    for (; p < end; p += 4) {
        int idx = p + q;
        if (idx < end) {
            int s = csr_src[idx];
            float ds = dinv[s];
            float4 v = x4[(size_t)s * 16 + m];
            a0.x = fmaf(ds, v.x, a0.x); a0.y = fmaf(ds, v.y, a0.y);
            a0.z = fmaf(ds, v.z, a0.z); a0.w = fmaf(ds, v.w, a0.w);
        }
    }
    a0.x += a1.x; a0.y += a1.y; a0.z += a1.z; a0.w += a1.w;
    // butterfly across quarters (replicates full sum to all lanes)
    a0.x += __shfl_xor(a0.x, 16); a0.y += __shfl_xor(a0.y, 16);
    a0.z += __shfl_xor(a0.z, 16); a0.w += __shfl_xor(a0.w, 16);
    a0.x += __shfl_xor(a0.x, 32); a0.y += __shfl_xor(a0.y, 32);
    a0.z += __shfl_xor(a0.z, 32); a0.w += __shfl_xor(a0.w, 32);
    float4 r;
    r.x = dd * fmaf(dd, self.x, a0.x);
    r.y = dd * fmaf(dd, self.y, a0.y);
    r.z = dd * fmaf(dd, self.z, a0.z);
    r.w = dd * fmaf(dd, self.w, a0.w);
    // GEMM1 via readlane broadcast: lane t (t<16) holds features 4t..4t+3 in r
    float acc = bias;
#pragma unroll
    for (int t = 0; t < 16; ++t) {
        acc = fmaf(rl(r.x, t), w[t].x, acc);
        acc = fmaf(rl(r.y, t), w[t].y, acc);
        acc = fmaf(rl(r.z, t), w[t].z, acc);
        acc = fmaf(rl(r.w, t), w[t].w, acc);
    }
    h1s[(size_t)node * F + lane] = dd * fmaxf(acc, 0.0f);
}

// ---- layer 2+3: pure-add gather + lin2 + relu + lin3 ----
__global__ __launch_bounds__(256, 4) void prop_lin23_kernel(
    const float4* __restrict__ h1s4, const int* __restrict__ rowptr,
    const int* __restrict__ csr_src, const float* __restrict__ dinv,
    const float* __restrict__ W2, const float* __restrict__ b2,
    const float* __restrict__ W3, const float* __restrict__ b3,
    float* __restrict__ out, int n) {
    int tid = threadIdx.x;
    int lane = tid & 63;
    int q = lane >> 4, m = lane & 15;
    int node = blockIdx.x * 4 + (tid >> 6);
    float4 w2[16];
#pragma unroll
    for (int t = 0; t < 16; ++t) w2[t] = *(const float4*)(W2 + (size_t)lane * F + 4 * t);
    // lane j holds W3[j&15][16*(j>>4) .. +15]
    float4 w3[4];
#pragma unroll
    for (int t = 0; t < 4; ++t)
        w3[t] = *(const float4*)(W3 + (size_t)m * F + q * 16 + 4 * t);
    float b2r = b2[lane];
    float b3r = b3[m];
    if (node >= n) return;
    int beg = rowptr[node], end = rowptr[node + 1];
    float dd = dinv[node];
    float4 self = h1s4[(size_t)node * 16 + m];
    float4 a0 = make_float4(0.f, 0.f, 0.f, 0.f);
    float4 a1 = make_float4(0.f, 0.f, 0.f, 0.f);
    int p = beg;
    for (; p + 8 <= end; p += 8) {
        int s0 = csr_src[p + q];
        int s1 = csr_src[p + 4 + q];
        float4 v0 = h1s4[(size_t)s0 * 16 + m];
        float4 v1 = h1s4[(size_t)s1 * 16 + m];
        a0.x += v0.x; a0.y += v0.y; a0.z += v0.z; a0.w += v0.w;
        a1.x += v1.x; a1.y += v1.y; a1.z += v1.z; a1.w += v1.w;
    }
    for (; p < end; p += 4) {
        int idx = p + q;
        if (idx < end) {
            int s = csr_src[idx];
            float4 v = h1s4[(size_t)s * 16 + m];
            a0.x += v.x; a0.y += v.y; a0.z += v.z; a0.w += v.w;
        }
    }
    a0.x += a1.x; a0.y += a1.y; a0.z += a1.z; a0.w += a1.w;
    a0.x += __shfl_xor(a0.x, 16); a0.y += __shfl_xor(a0.y, 16);
    a0.z += __shfl_xor(a0.z, 16); a0.w += __shfl_xor(a0.w, 16);
    a0.x += __shfl_xor(a0.x, 32); a0.y += __shfl_xor(a0.y, 32);
    a0.z += __shfl_xor(a0.z, 32); a0.w += __shfl_xor(a0.w, 32);
    float4 r;
    r.x = dd * (a0.x + self.x);
    r.y = dd * (a0.y + self.y);
    r.z = dd * (a0.z + self.z);
    r.w = dd * (a0.w + self.w);
    // GEMM2 via readlane
    float acc = b2r;
#pragma unroll
    for (int t = 0; t < 16; ++t) {
        acc = fmaf(rl(r.x, t), w2[t].x, acc);
        acc = fmaf(rl(r.y, t), w2[t].y, acc);
        acc = fmaf(rl(r.z, t), w2[t].z, acc);
        acc = fmaf(rl(r.w, t), w2[t].w, acc);
    }
    float h2 = fmaxf(acc, 0.0f);   // lane j holds h2[j]
    // GEMM3: lane j accumulates over k = 16q..16q+15 for output c = j&15
    const float* w3f = (const float*)w3;
    float partial = 0.0f;
    int qb = lane & 48;            // q*16
#pragma unroll
    for (int t = 0; t < 16; ++t) {
        float hv = __shfl(h2, qb + t);
        partial = fmaf(hv, w3f[t], partial);
    }
    partial += __shfl_xor(partial, 16);
    partial += __shfl_xor(partial, 32);
    if (lane < 16) out[(size_t)node * C + lane] = b3r + partial;
}

extern "C" void kernel_launch(void* const* d_in, const int* in_sizes, int n_in,
                              void* d_out, int out_size, void* d_ws, size_t ws_size,
                              hipStream_t stream) {
    const float* x  = (const float*)d_in[0];
    const int* edge = (const int*)d_in[1];
    const float* W1 = (const float*)d_in[2];
    const float* b1 = (const float*)d_in[3];
    const float* W2 = (const float*)d_in[4];
    const float* b2 = (const float*)d_in[5];
    const float* W3 = (const float*)d_in[6];
    const float* b3 = (const float*)d_in[7];
    float* out = (float*)d_out;

    int n = in_sizes[0] / F;        // 100000
    int E = in_sizes[1] / 2;        // 1600000
    const int* src = edge;
    const int* dst = edge + E;

    int nb = (n + SCAN_B - 1) / SCAN_B;

    char* ws = (char*)d_ws;
    size_t o = 0;
    auto alloc = [&](size_t bytes) { char* p = ws + o; o += (bytes + 255) & ~(size_t)255; return p; };
    int*   deg     = (int*)  alloc((size_t)n * 4);
    int*   part    = (int*)  alloc((size_t)n * 4);
    int*   bsum    = (int*)  alloc(256 * 4);
    int*   rowptr  = (int*)  alloc((size_t)(n + 1) * 4);
    int*   cursor  = (int*)  alloc((size_t)n * 4);
    int*   csr_src = (int*)  alloc((size_t)E * 4);
    float* dinv    = (float*)alloc((size_t)n * 4);
    float* h1s     = (float*)alloc((size_t)n * F * 4);

    hipMemsetAsync(deg, 0, (size_t)n * 4, stream);
    deg_kernel<<<(E / 4 + 255) / 256, 256, 0, stream>>>(dst, deg, E);

    scan1_kernel<<<nb, 256, 0, stream>>>(deg, part, bsum, n);
    scan2_kernel<<<1, 256, 0, stream>>>(bsum, nb);
    scan3_kernel<<<(n + 255) / 256, 256, 0, stream>>>(part, bsum, deg, rowptr, cursor, dinv, n, E);

    fill_kernel<<<(E / 4 + 255) / 256, 256, 0, stream>>>(src, dst, cursor, csr_src, E);

    prop_lin1_kernel<<<(n + 3) / 4, 256, 0, stream>>>(
        (const float4*)x, rowptr, csr_src, dinv, W1, b1, h1s, n);
    prop_lin23_kernel<<<(n + 3) / 4, 256, 0, stream>>>(
        (const float4*)h1s, rowptr, csr_src, dinv, W2, b2, W3, b3, out, n);
}

// Round 5
// 324.284 us; speedup vs baseline: 2.2076x; 2.2076x over previous
//
#include <hip/hip_runtime.h>

// SGC forward, GEMM-commuted form:
//   prop(x) @ W^T == prop(x @ W^T)   (propagation is linear, dinv diagonal)
//   dinv[i] = rsqrt(indeg[i]+1)
//   y1  = dinv .* (x @ W1^T)                       (dense GEMM, scaled epilogue)
//   h1s = dinv .* relu( dinv[d]*(sum y1[s] + y1[d]) + b1 )   (pure-add gather)
//   y2  = h1s @ W2^T                               (dense GEMM)
//   h2  = relu( dinv[d]*(sum y2[s] + y2[d]) + b2 )
//   out = h2 @ W3^T + b3                           (fused in gather2 via shfl)
// CSR built via counting sort; fill is atomic-free (rank recorded in histogram).

#define F 64
#define C 16
#define SCAN_B 1024

__device__ __forceinline__ float rl(float v, int l) {
    return __uint_as_float(__builtin_amdgcn_readlane(__float_as_uint(v), l));
}

// ---- histogram + per-edge rank (one atomic pass) ----
__global__ void degrank_kernel(const int* __restrict__ dst, int* __restrict__ deg,
                               int* __restrict__ rank, int E) {
    int i = (blockIdx.x * blockDim.x + threadIdx.x) * 4;
    if (i + 4 <= E) {
        int4 d = *(const int4*)(dst + i);
        rank[i]     = atomicAdd(&deg[d.x], 1);
        rank[i + 1] = atomicAdd(&deg[d.y], 1);
        rank[i + 2] = atomicAdd(&deg[d.z], 1);
        rank[i + 3] = atomicAdd(&deg[d.w], 1);
    } else {
        for (int k = i; k < E; ++k) rank[k] = atomicAdd(&deg[dst[k]], 1);
    }
}

// ---- exclusive scan of deg -> rowptr ----
__global__ __launch_bounds__(256) void scan1_kernel(const int* __restrict__ deg,
                                                    int* __restrict__ part,
                                                    int* __restrict__ bsum, int n) {
    __shared__ int ts[256];
    int b = blockIdx.x, t = threadIdx.x;
    int base = b * SCAN_B + t * 4;
    int v[4], sum = 0;
#pragma unroll
    for (int k = 0; k < 4; ++k) { int i = base + k; v[k] = (i < n) ? deg[i] : 0; sum += v[k]; }
    ts[t] = sum;
    __syncthreads();
    for (int off = 1; off < 256; off <<= 1) {
        int add = (t >= off) ? ts[t - off] : 0;
        __syncthreads();
        ts[t] += add;
        __syncthreads();
    }
    int run = ts[t] - sum;
#pragma unroll
    for (int k = 0; k < 4; ++k) { int i = base + k; if (i < n) part[i] = run; run += v[k]; }
    if (t == 255) bsum[b] = ts[255];
}

__global__ __launch_bounds__(256) void scan2_kernel(int* __restrict__ bsum, int nb) {
    __shared__ int ts[256];
    int t = threadIdx.x;
    int v = (t < nb) ? bsum[t] : 0;
    ts[t] = v;
    __syncthreads();
    for (int off = 1; off < 256; off <<= 1) {
        int add = (t >= off) ? ts[t - off] : 0;
        __syncthreads();
        ts[t] += add;
        __syncthreads();
    }
    if (t < nb) bsum[t] = ts[t] - v;
}

__global__ void scan3_kernel(const int* __restrict__ part, const int* __restrict__ bsum,
                             const int* __restrict__ deg, int* __restrict__ rowptr,
                             float* __restrict__ dinv, int n, int E) {
    int i = blockIdx.x * blockDim.x + threadIdx.x;
    if (i < n) {
        rowptr[i] = part[i] + bsum[i / SCAN_B];
        dinv[i] = rsqrtf((float)deg[i] + 1.0f);
    }
    if (i == 0) rowptr[n] = E;
}

// ---- atomic-free bucket fill ----
__global__ void fill_kernel(const int* __restrict__ src, const int* __restrict__ dst,
                            const int* __restrict__ rank, const int* __restrict__ rowptr,
                            int* __restrict__ csr_src, int E) {
    int i = (blockIdx.x * blockDim.x + threadIdx.x) * 4;
    if (i + 4 <= E) {
        int4 s = *(const int4*)(src + i);
        int4 d = *(const int4*)(dst + i);
        int4 r = *(const int4*)(rank + i);
        csr_src[rowptr[d.x] + r.x] = s.x;
        csr_src[rowptr[d.y] + r.y] = s.y;
        csr_src[rowptr[d.z] + r.z] = s.z;
        csr_src[rowptr[d.w] + r.w] = s.w;
    } else {
        for (int k = i; k < E; ++k) csr_src[rowptr[dst[k]] + rank[k]] = src[k];
    }
}

// ---- dense GEMM: out[i][j] = (in[i] . W[j]) * (SCALE ? scale[i] : 1) ----
// Row replicated across quarters -> readlane(v, t) is wave-uniform & legal.
// Weights: 16 float4 per lane (W[lane][:]) loaded once per wave.
template <bool SCALE>
__global__ __launch_bounds__(256) void gemm_kernel(
    const float4* __restrict__ in4, const float* __restrict__ W,
    const float* __restrict__ scale, float* __restrict__ out, int n) {
    int tid = threadIdx.x;
    int lane = tid & 63;
    int m = lane & 15;
    float4 w[16];
#pragma unroll
    for (int t = 0; t < 16; ++t) w[t] = *(const float4*)(W + (size_t)lane * F + 4 * t);
    int gw = blockIdx.x * 4 + (tid >> 6);
    int nw = gridDim.x * 4;
    int node = gw;
    if (node >= n) return;
    float4 v = in4[(size_t)node * 16 + m];
    while (true) {
        int nxt = node + nw;
        float4 vn;
        if (nxt < n) vn = in4[(size_t)nxt * 16 + m];   // prefetch next row
        float acc = 0.0f;
#pragma unroll
        for (int t = 0; t < 16; ++t) {
            acc = fmaf(rl(v.x, t), w[t].x, acc);
            acc = fmaf(rl(v.y, t), w[t].y, acc);
            acc = fmaf(rl(v.z, t), w[t].z, acc);
            acc = fmaf(rl(v.w, t), w[t].w, acc);
        }
        if (SCALE) acc *= scale[node];
        out[(size_t)node * F + lane] = acc;
        if (nxt >= n) break;
        v = vn;
        node = nxt;
    }
}

// ---- gather1: pure-add gather of y1s + bias + relu + dinv scale -> h1s ----
__global__ __launch_bounds__(256) void gather1_kernel(
    const float4* __restrict__ y4, const int* __restrict__ rowptr,
    const int* __restrict__ csr_src, const float* __restrict__ dinv,
    const float* __restrict__ b1, float* __restrict__ h1s, int n) {
    int tid = threadIdx.x;
    int lane = tid & 63;
    int q = lane >> 4, m = lane & 15;
    float4 bias = *(const float4*)(b1 + 4 * m);
    int gw = blockIdx.x * 4 + (tid >> 6);
    int nw = gridDim.x * 4;
    for (int node = gw; node < n; node += nw) {
        int beg = rowptr[node], end = rowptr[node + 1];
        float4 a0 = {0, 0, 0, 0}, a1 = {0, 0, 0, 0}, a2 = {0, 0, 0, 0}, a3 = {0, 0, 0, 0};
        int p = beg;
        for (; p + 16 <= end; p += 16) {
            int s0 = csr_src[p + q];
            int s1 = csr_src[p + 4 + q];
            int s2 = csr_src[p + 8 + q];
            int s3 = csr_src[p + 12 + q];
            float4 v0 = y4[(size_t)s0 * 16 + m];
            float4 v1 = y4[(size_t)s1 * 16 + m];
            float4 v2 = y4[(size_t)s2 * 16 + m];
            float4 v3 = y4[(size_t)s3 * 16 + m];
            a0.x += v0.x; a0.y += v0.y; a0.z += v0.z; a0.w += v0.w;
            a1.x += v1.x; a1.y += v1.y; a1.z += v1.z; a1.w += v1.w;
            a2.x += v2.x; a2.y += v2.y; a2.z += v2.z; a2.w += v2.w;
            a3.x += v3.x; a3.y += v3.y; a3.z += v3.z; a3.w += v3.w;
        }
        for (; p < end; p += 4) {
            int idx = p + q;
            if (idx < end) {
                int s = csr_src[idx];
                float4 v = y4[(size_t)s * 16 + m];
                a0.x += v.x; a0.y += v.y; a0.z += v.z; a0.w += v.w;
            }
        }
        a0.x += a1.x + a2.x + a3.x;
        a0.y += a1.y + a2.y + a3.y;
        a0.z += a1.z + a2.z + a3.z;
        a0.w += a1.w + a2.w + a3.w;
        a0.x += __shfl_xor(a0.x, 16); a0.y += __shfl_xor(a0.y, 16);
        a0.z += __shfl_xor(a0.z, 16); a0.w += __shfl_xor(a0.w, 16);
        a0.x += __shfl_xor(a0.x, 32); a0.y += __shfl_xor(a0.y, 32);
        a0.z += __shfl_xor(a0.z, 32); a0.w += __shfl_xor(a0.w, 32);
        float dd = dinv[node];
        float4 self = y4[(size_t)node * 16 + m];
        if (q == 0) {
            float4 r;
            r.x = dd * fmaxf(fmaf(dd, a0.x + self.x, bias.x), 0.0f);
            r.y = dd * fmaxf(fmaf(dd, a0.y + self.y, bias.y), 0.0f);
            r.z = dd * fmaxf(fmaf(dd, a0.z + self.z, bias.z), 0.0f);
            r.w = dd * fmaxf(fmaf(dd, a0.w + self.w, bias.w), 0.0f);
            *(float4*)(h1s + (size_t)node * F + 4 * m) = r;
        }
    }
}

// ---- gather2: pure-add gather of y2 + bias + relu + W3 GEMM (shfl) -> out ----
__global__ __launch_bounds__(256) void gather2_kernel(
    const float4* __restrict__ y4, const int* __restrict__ rowptr,
    const int* __restrict__ csr_src, const float* __restrict__ dinv,
    const float* __restrict__ b2, const float* __restrict__ W3,
    const float* __restrict__ b3, float* __restrict__ out, int n) {
    int tid = threadIdx.x;
    int lane = tid & 63;
    int q = lane >> 4, m = lane & 15;
    float4 bias = *(const float4*)(b2 + 4 * m);
    float4 w3[4];
#pragma unroll
    for (int t = 0; t < 4; ++t)
        w3[t] = *(const float4*)(W3 + (size_t)m * F + 16 * q + 4 * t);
    float b3r = b3[m];
    int gw = blockIdx.x * 4 + (tid >> 6);
    int nw = gridDim.x * 4;
    for (int node = gw; node < n; node += nw) {
        int beg = rowptr[node], end = rowptr[node + 1];
        float4 a0 = {0, 0, 0, 0}, a1 = {0, 0, 0, 0}, a2 = {0, 0, 0, 0}, a3 = {0, 0, 0, 0};
        int p = beg;
        for (; p + 16 <= end; p += 16) {
            int s0 = csr_src[p + q];
            int s1 = csr_src[p + 4 + q];
            int s2 = csr_src[p + 8 + q];
            int s3 = csr_src[p + 12 + q];
            float4 v0 = y4[(size_t)s0 * 16 + m];
            float4 v1 = y4[(size_t)s1 * 16 + m];
            float4 v2 = y4[(size_t)s2 * 16 + m];
            float4 v3 = y4[(size_t)s3 * 16 + m];
            a0.x += v0.x; a0.y += v0.y; a0.z += v0.z; a0.w += v0.w;
            a1.x += v1.x; a1.y += v1.y; a1.z += v1.z; a1.w += v1.w;
            a2.x += v2.x; a2.y += v2.y; a2.z += v2.z; a2.w += v2.w;
            a3.x += v3.x; a3.y += v3.y; a3.z += v3.z; a3.w += v3.w;
        }
        for (; p < end; p += 4) {
            int idx = p + q;
            if (idx < end) {
                int s = csr_src[idx];
                float4 v = y4[(size_t)s * 16 + m];
                a0.x += v.x; a0.y += v.y; a0.z += v.z; a0.w += v.w;
            }
        }
        a0.x += a1.x + a2.x + a3.x;
        a0.y += a1.y + a2.y + a3.y;
        a0.z += a1.z + a2.z + a3.z;
        a0.w += a1.w + a2.w + a3.w;
        a0.x += __shfl_xor(a0.x, 16); a0.y += __shfl_xor(a0.y, 16);
        a0.z += __shfl_xor(a0.z, 16); a0.w += __shfl_xor(a0.w, 16);
        a0.x += __shfl_xor(a0.x, 32); a0.y += __shfl_xor(a0.y, 32);
        a0.z += __shfl_xor(a0.z, 32); a0.w += __shfl_xor(a0.w, 32);
        float dd = dinv[node];
        float4 self = y4[(size_t)node * 16 + m];
        float4 h;
        h.x = fmaxf(fmaf(dd, a0.x + self.x, bias.x), 0.0f);
        h.y = fmaxf(fmaf(dd, a0.y + self.y, bias.y), 0.0f);
        h.z = fmaxf(fmaf(dd, a0.z + self.z, bias.z), 0.0f);
        h.w = fmaxf(fmaf(dd, a0.w + self.w, bias.w), 0.0f);
        // h holds h2 features [4m..4m+3], replicated in every quarter.
        // Lane (q,m): partial of out[m] over features [16q, 16q+16).
        float partial = 0.0f;
#pragma unroll
        for (int t = 0; t < 4; ++t) {
            int sl = 4 * q + t;  // lane (quarter 0) holding features 16q+4t..+3
            partial = fmaf(__shfl(h.x, sl), w3[t].x, partial);
            partial = fmaf(__shfl(h.y, sl), w3[t].y, partial);
            partial = fmaf(__shfl(h.z, sl), w3[t].z, partial);
            partial = fmaf(__shfl(h.w, sl), w3[t].w, partial);
        }
        partial += __shfl_xor(partial, 16);
        partial += __shfl_xor(partial, 32);
        if (q == 0) out[(size_t)node * C + m] = partial + b3r;
    }
}

extern "C" void kernel_launch(void* const* d_in, const int* in_sizes, int n_in,
                              void* d_out, int out_size, void* d_ws, size_t ws_size,
                              hipStream_t stream) {
    const float* x  = (const float*)d_in[0];
    const int* edge = (const int*)d_in[1];
    const float* W1 = (const float*)d_in[2];
    const float* b1 = (const float*)d_in[3];
    const float* W2 = (const float*)d_in[4];
    const float* b2 = (const float*)d_in[5];
    const float* W3 = (const float*)d_in[6];
    const float* b3 = (const float*)d_in[7];
    float* out = (float*)d_out;

    int n = in_sizes[0] / F;        // 100000
    int E = in_sizes[1] / 2;        // 1600000
    const int* src = edge;
    const int* dst = edge + E;

    int nb = (n + SCAN_B - 1) / SCAN_B;

    char* ws = (char*)d_ws;
    size_t o = 0;
    auto alloc = [&](size_t bytes) { char* p = ws + o; o += (bytes + 255) & ~(size_t)255; return p; };
    int*   deg     = (int*)  alloc((size_t)n * 4);
    int*   rank    = (int*)  alloc((size_t)E * 4);
    int*   part    = (int*)  alloc((size_t)n * 4);
    int*   bsum    = (int*)  alloc(256 * 4);
    int*   rowptr  = (int*)  alloc((size_t)(n + 1) * 4);
    int*   csr_src = (int*)  alloc((size_t)E * 4);
    float* dinv    = (float*)alloc((size_t)n * 4);
    float* y1      = (float*)alloc((size_t)n * F * 4);   // reused as y2
    float* h1s     = (float*)alloc((size_t)n * F * 4);
    float* y2      = y1;                                  // y1 dead after gather1

    hipMemsetAsync(deg, 0, (size_t)n * 4, stream);
    degrank_kernel<<<(E / 4 + 255) / 256, 256, 0, stream>>>(dst, deg, rank, E);

    scan1_kernel<<<nb, 256, 0, stream>>>(deg, part, bsum, n);
    scan2_kernel<<<1, 256, 0, stream>>>(bsum, nb);
    scan3_kernel<<<(n + 255) / 256, 256, 0, stream>>>(part, bsum, deg, rowptr, dinv, n, E);

    // y1 = dinv .* (x @ W1^T)   (needs dinv; independent of fill)
    gemm_kernel<true><<<2048, 256, 0, stream>>>((const float4*)x, W1, dinv, y1, n);

    fill_kernel<<<(E / 4 + 255) / 256, 256, 0, stream>>>(src, dst, rank, rowptr, csr_src, E);

    gather1_kernel<<<2048, 256, 0, stream>>>(
        (const float4*)y1, rowptr, csr_src, dinv, b1, h1s, n);

    // y2 = h1s @ W2^T
    gemm_kernel<false><<<2048, 256, 0, stream>>>((const float4*)h1s, W2, nullptr, y2, n);

    gather2_kernel<<<2048, 256, 0, stream>>>(
        (const float4*)y2, rowptr, csr_src, dinv, b2, W3, b3, out, n);
}

// Round 6
// 300.539 us; speedup vs baseline: 2.3820x; 1.0790x over previous
//
#include <hip/hip_runtime.h>
#include <hip/hip_fp16.h>

// SGC forward, GEMM-commuted form with fp16 gather tables:
//   prop(x) @ W^T == prop(x @ W^T)   (propagation is linear, dinv diagonal)
//   dinv[i] = rsqrt(indeg[i]+1)
//   y1  = fp16( dinv .* (x @ W1^T) )               (dense GEMM, scaled epilogue)
//   h1s = dinv .* relu( dinv[d]*(sum y1[s] + y1[d]) + b1 )   (pure-add gather, fp32 accum)
//   y2  = fp16( h1s @ W2^T )                       (dense GEMM)
//   h2  = relu( dinv[d]*(sum y2[s] + y2[d]) + b2 )
//   out = h2 @ W3^T + b3                           (fused in gather2 via shfl)
// fp16 halves the random-gather fetch volume (the round-5 bottleneck:
// FETCH_SIZE 190MB vs 32MB working set). Accumulation is fp32 throughout.

#define F 64
#define C 16
#define SCAN_B 1024

__device__ __forceinline__ float rl(float v, int l) {
    return __uint_as_float(__builtin_amdgcn_readlane(__float_as_uint(v), l));
}

// load 4 consecutive fp16 features (8B) and widen to float4
__device__ __forceinline__ float4 ld_h4(const float2* base, size_t idx) {
    float2 raw = base[idx];
    __half2 lo = __builtin_bit_cast(__half2, raw.x);
    __half2 hi = __builtin_bit_cast(__half2, raw.y);
    float2 f0 = __half22float2(lo);
    float2 f1 = __half22float2(hi);
    return make_float4(f0.x, f0.y, f1.x, f1.y);
}

// ---- histogram + per-edge rank (one atomic pass) ----
__global__ void degrank_kernel(const int* __restrict__ dst, int* __restrict__ deg,
                               int* __restrict__ rank, int E) {
    int i = (blockIdx.x * blockDim.x + threadIdx.x) * 4;
    if (i + 4 <= E) {
        int4 d = *(const int4*)(dst + i);
        rank[i]     = atomicAdd(&deg[d.x], 1);
        rank[i + 1] = atomicAdd(&deg[d.y], 1);
        rank[i + 2] = atomicAdd(&deg[d.z], 1);
        rank[i + 3] = atomicAdd(&deg[d.w], 1);
    } else {
        for (int k = i; k < E; ++k) rank[k] = atomicAdd(&deg[dst[k]], 1);
    }
}

// ---- exclusive scan of deg -> rowptr ----
__global__ __launch_bounds__(256) void scan1_kernel(const int* __restrict__ deg,
                                                    int* __restrict__ part,
                                                    int* __restrict__ bsum, int n) {
    __shared__ int ts[256];
    int b = blockIdx.x, t = threadIdx.x;
    int base = b * SCAN_B + t * 4;
    int v[4], sum = 0;
#pragma unroll
    for (int k = 0; k < 4; ++k) { int i = base + k; v[k] = (i < n) ? deg[i] : 0; sum += v[k]; }
    ts[t] = sum;
    __syncthreads();
    for (int off = 1; off < 256; off <<= 1) {
        int add = (t >= off) ? ts[t - off] : 0;
        __syncthreads();
        ts[t] += add;
        __syncthreads();
    }
    int run = ts[t] - sum;
#pragma unroll
    for (int k = 0; k < 4; ++k) { int i = base + k; if (i < n) part[i] = run; run += v[k]; }
    if (t == 255) bsum[b] = ts[255];
}

__global__ __launch_bounds__(256) void scan2_kernel(int* __restrict__ bsum, int nb) {
    __shared__ int ts[256];
    int t = threadIdx.x;
    int v = (t < nb) ? bsum[t] : 0;
    ts[t] = v;
    __syncthreads();
    for (int off = 1; off < 256; off <<= 1) {
        int add = (t >= off) ? ts[t - off] : 0;
        __syncthreads();
        ts[t] += add;
        __syncthreads();
    }
    if (t < nb) bsum[t] = ts[t] - v;
}

__global__ void scan3_kernel(const int* __restrict__ part, const int* __restrict__ bsum,
                             const int* __restrict__ deg, int* __restrict__ rowptr,
                             float* __restrict__ dinv, int n, int E) {
    int i = blockIdx.x * blockDim.x + threadIdx.x;
    if (i < n) {
        rowptr[i] = part[i] + bsum[i / SCAN_B];
        dinv[i] = rsqrtf((float)deg[i] + 1.0f);
    }
    if (i == 0) rowptr[n] = E;
}

// ---- atomic-free bucket fill ----
__global__ void fill_kernel(const int* __restrict__ src, const int* __restrict__ dst,
                            const int* __restrict__ rank, const int* __restrict__ rowptr,
                            int* __restrict__ csr_src, int E) {
    int i = (blockIdx.x * blockDim.x + threadIdx.x) * 4;
    if (i + 4 <= E) {
        int4 s = *(const int4*)(src + i);
        int4 d = *(const int4*)(dst + i);
        int4 r = *(const int4*)(rank + i);
        csr_src[rowptr[d.x] + r.x] = s.x;
        csr_src[rowptr[d.y] + r.y] = s.y;
        csr_src[rowptr[d.z] + r.z] = s.z;
        csr_src[rowptr[d.w] + r.w] = s.w;
    } else {
        for (int k = i; k < E; ++k) csr_src[rowptr[dst[k]] + rank[k]] = src[k];
    }
}

// ---- dense GEMM: yout[i][j] = fp16( (in[i] . W[j]) * (SCALE ? scale[i] : 1) ) ----
// Row replicated across quarters -> readlane(v, t) is wave-uniform & legal.
template <bool SCALE>
__global__ __launch_bounds__(256) void gemm_kernel(
    const float4* __restrict__ in4, const float* __restrict__ W,
    const float* __restrict__ scale, __half* __restrict__ yout, int n) {
    int tid = threadIdx.x;
    int lane = tid & 63;
    int m = lane & 15;
    float4 w[16];
#pragma unroll
    for (int t = 0; t < 16; ++t) w[t] = *(const float4*)(W + (size_t)lane * F + 4 * t);
    int gw = blockIdx.x * 4 + (tid >> 6);
    int nw = gridDim.x * 4;
    int node = gw;
    if (node >= n) return;
    float4 v = in4[(size_t)node * 16 + m];
    while (true) {
        int nxt = node + nw;
        float4 vn;
        if (nxt < n) vn = in4[(size_t)nxt * 16 + m];   // prefetch next row
        float acc = 0.0f;
#pragma unroll
        for (int t = 0; t < 16; ++t) {
            acc = fmaf(rl(v.x, t), w[t].x, acc);
            acc = fmaf(rl(v.y, t), w[t].y, acc);
            acc = fmaf(rl(v.z, t), w[t].z, acc);
            acc = fmaf(rl(v.w, t), w[t].w, acc);
        }
        if (SCALE) acc *= scale[node];
        yout[(size_t)node * F + lane] = __float2half(acc);
        if (nxt >= n) break;
        v = vn;
        node = nxt;
    }
}

// ---- gather1: pure-add fp16 gather of y1 + bias + relu + dinv scale -> h1s (fp32) ----
__global__ __launch_bounds__(256) void gather1_kernel(
    const float2* __restrict__ y4, const int* __restrict__ rowptr,
    const int* __restrict__ csr_src, const float* __restrict__ dinv,
    const float* __restrict__ b1, float* __restrict__ h1s, int n) {
    int tid = threadIdx.x;
    int lane = tid & 63;
    int q = lane >> 4, m = lane & 15;
    float4 bias = *(const float4*)(b1 + 4 * m);
    int gw = blockIdx.x * 4 + (tid >> 6);
    int nw = gridDim.x * 4;
    for (int node = gw; node < n; node += nw) {
        int beg = rowptr[node], end = rowptr[node + 1];
        float4 a0 = {0, 0, 0, 0}, a1 = {0, 0, 0, 0}, a2 = {0, 0, 0, 0}, a3 = {0, 0, 0, 0};
        int p = beg;
        for (; p + 16 <= end; p += 16) {
            int s0 = csr_src[p + q];
            int s1 = csr_src[p + 4 + q];
            int s2 = csr_src[p + 8 + q];
            int s3 = csr_src[p + 12 + q];
            float4 v0 = ld_h4(y4, (size_t)s0 * 16 + m);
            float4 v1 = ld_h4(y4, (size_t)s1 * 16 + m);
            float4 v2 = ld_h4(y4, (size_t)s2 * 16 + m);
            float4 v3 = ld_h4(y4, (size_t)s3 * 16 + m);
            a0.x += v0.x; a0.y += v0.y; a0.z += v0.z; a0.w += v0.w;
            a1.x += v1.x; a1.y += v1.y; a1.z += v1.z; a1.w += v1.w;
            a2.x += v2.x; a2.y += v2.y; a2.z += v2.z; a2.w += v2.w;
            a3.x += v3.x; a3.y += v3.y; a3.z += v3.z; a3.w += v3.w;
        }
        for (; p < end; p += 4) {
            int idx = p + q;
            if (idx < end) {
                int s = csr_src[idx];
                float4 v = ld_h4(y4, (size_t)s * 16 + m);
                a0.x += v.x; a0.y += v.y; a0.z += v.z; a0.w += v.w;
            }
        }
        a0.x += a1.x + a2.x + a3.x;
        a0.y += a1.y + a2.y + a3.y;
        a0.z += a1.z + a2.z + a3.z;
        a0.w += a1.w + a2.w + a3.w;
        a0.x += __shfl_xor(a0.x, 16); a0.y += __shfl_xor(a0.y, 16);
        a0.z += __shfl_xor(a0.z, 16); a0.w += __shfl_xor(a0.w, 16);
        a0.x += __shfl_xor(a0.x, 32); a0.y += __shfl_xor(a0.y, 32);
        a0.z += __shfl_xor(a0.z, 32); a0.w += __shfl_xor(a0.w, 32);
        float dd = dinv[node];
        float4 self = ld_h4(y4, (size_t)node * 16 + m);
        if (q == 0) {
            float4 r;
            r.x = dd * fmaxf(fmaf(dd, a0.x + self.x, bias.x), 0.0f);
            r.y = dd * fmaxf(fmaf(dd, a0.y + self.y, bias.y), 0.0f);
            r.z = dd * fmaxf(fmaf(dd, a0.z + self.z, bias.z), 0.0f);
            r.w = dd * fmaxf(fmaf(dd, a0.w + self.w, bias.w), 0.0f);
            *(float4*)(h1s + (size_t)node * F + 4 * m) = r;
        }
    }
}

// ---- gather2: pure-add fp16 gather of y2 + bias + relu + W3 GEMM (shfl) -> out ----
__global__ __launch_bounds__(256) void gather2_kernel(
    const float2* __restrict__ y4, const int* __restrict__ rowptr,
    const int* __restrict__ csr_src, const float* __restrict__ dinv,
    const float* __restrict__ b2, const float* __restrict__ W3,
    const float* __restrict__ b3, float* __restrict__ out, int n) {
    int tid = threadIdx.x;
    int lane = tid & 63;
    int q = lane >> 4, m = lane & 15;
    float4 bias = *(const float4*)(b2 + 4 * m);
    float4 w3[4];
#pragma unroll
    for (int t = 0; t < 4; ++t)
        w3[t] = *(const float4*)(W3 + (size_t)m * F + 16 * q + 4 * t);
    float b3r = b3[m];
    int gw = blockIdx.x * 4 + (tid >> 6);
    int nw = gridDim.x * 4;
    for (int node = gw; node < n; node += nw) {
        int beg = rowptr[node], end = rowptr[node + 1];
        float4 a0 = {0, 0, 0, 0}, a1 = {0, 0, 0, 0}, a2 = {0, 0, 0, 0}, a3 = {0, 0, 0, 0};
        int p = beg;
        for (; p + 16 <= end; p += 16) {
            int s0 = csr_src[p + q];
            int s1 = csr_src[p + 4 + q];
            int s2 = csr_src[p + 8 + q];
            int s3 = csr_src[p + 12 + q];
            float4 v0 = ld_h4(y4, (size_t)s0 * 16 + m);
            float4 v1 = ld_h4(y4, (size_t)s1 * 16 + m);
            float4 v2 = ld_h4(y4, (size_t)s2 * 16 + m);
            float4 v3 = ld_h4(y4, (size_t)s3 * 16 + m);
            a0.x += v0.x; a0.y += v0.y; a0.z += v0.z; a0.w += v0.w;
            a1.x += v1.x; a1.y += v1.y; a1.z += v1.z; a1.w += v1.w;
            a2.x += v2.x; a2.y += v2.y; a2.z += v2.z; a2.w += v2.w;
            a3.x += v3.x; a3.y += v3.y; a3.z += v3.z; a3.w += v3.w;
        }
        for (; p < end; p += 4) {
            int idx = p + q;
            if (idx < end) {
                int s = csr_src[idx];
                float4 v = ld_h4(y4, (size_t)s * 16 + m);
                a0.x += v.x; a0.y += v.y; a0.z += v.z; a0.w += v.w;
            }
        }
        a0.x += a1.x + a2.x + a3.x;
        a0.y += a1.y + a2.y + a3.y;
        a0.z += a1.z + a2.z + a3.z;
        a0.w += a1.w + a2.w + a3.w;
        a0.x += __shfl_xor(a0.x, 16); a0.y += __shfl_xor(a0.y, 16);
        a0.z += __shfl_xor(a0.z, 16); a0.w += __shfl_xor(a0.w, 16);
        a0.x += __shfl_xor(a0.x, 32); a0.y += __shfl_xor(a0.y, 32);
        a0.z += __shfl_xor(a0.z, 32); a0.w += __shfl_xor(a0.w, 32);
        float dd = dinv[node];
        float4 self = ld_h4(y4, (size_t)node * 16 + m);
        float4 h;
        h.x = fmaxf(fmaf(dd, a0.x + self.x, bias.x), 0.0f);
        h.y = fmaxf(fmaf(dd, a0.y + self.y, bias.y), 0.0f);
        h.z = fmaxf(fmaf(dd, a0.z + self.z, bias.z), 0.0f);
        h.w = fmaxf(fmaf(dd, a0.w + self.w, bias.w), 0.0f);
        // h holds h2 features [4m..4m+3], replicated in every quarter.
        // Lane (q,m): partial of out[m] over features [16q, 16q+16).
        float partial = 0.0f;
#pragma unroll
        for (int t = 0; t < 4; ++t) {
            int sl = 4 * q + t;  // lane (quarter 0) holding features 16q+4t..+3
            partial = fmaf(__shfl(h.x, sl), w3[t].x, partial);
            partial = fmaf(__shfl(h.y, sl), w3[t].y, partial);
            partial = fmaf(__shfl(h.z, sl), w3[t].z, partial);
            partial = fmaf(__shfl(h.w, sl), w3[t].w, partial);
        }
        partial += __shfl_xor(partial, 16);
        partial += __shfl_xor(partial, 32);
        if (q == 0) out[(size_t)node * C + m] = partial + b3r;
    }
}

extern "C" void kernel_launch(void* const* d_in, const int* in_sizes, int n_in,
                              void* d_out, int out_size, void* d_ws, size_t ws_size,
                              hipStream_t stream) {
    const float* x  = (const float*)d_in[0];
    const int* edge = (const int*)d_in[1];
    const float* W1 = (const float*)d_in[2];
    const float* b1 = (const float*)d_in[3];
    const float* W2 = (const float*)d_in[4];
    const float* b2 = (const float*)d_in[5];
    const float* W3 = (const float*)d_in[6];
    const float* b3 = (const float*)d_in[7];
    float* out = (float*)d_out;

    int n = in_sizes[0] / F;        // 100000
    int E = in_sizes[1] / 2;        // 1600000
    const int* src = edge;
    const int* dst = edge + E;

    int nb = (n + SCAN_B - 1) / SCAN_B;

    char* ws = (char*)d_ws;
    size_t o = 0;
    auto alloc = [&](size_t bytes) { char* p = ws + o; o += (bytes + 255) & ~(size_t)255; return p; };
    int*    deg     = (int*)   alloc((size_t)n * 4);
    int*    rank    = (int*)   alloc((size_t)E * 4);
    int*    part    = (int*)   alloc((size_t)n * 4);
    int*    bsum    = (int*)   alloc(256 * 4);
    int*    rowptr  = (int*)   alloc((size_t)(n + 1) * 4);
    int*    csr_src = (int*)   alloc((size_t)E * 4);
    float*  dinv    = (float*) alloc((size_t)n * 4);
    __half* y1      = (__half*)alloc((size_t)n * F * 2);   // reused as y2
    float*  h1s     = (float*) alloc((size_t)n * F * 4);
    __half* y2      = y1;                                   // y1 dead after gather1

    hipMemsetAsync(deg, 0, (size_t)n * 4, stream);
    degrank_kernel<<<(E / 4 + 255) / 256, 256, 0, stream>>>(dst, deg, rank, E);

    scan1_kernel<<<nb, 256, 0, stream>>>(deg, part, bsum, n);
    scan2_kernel<<<1, 256, 0, stream>>>(bsum, nb);
    scan3_kernel<<<(n + 255) / 256, 256, 0, stream>>>(part, bsum, deg, rowptr, dinv, n, E);

    // y1 = fp16( dinv .* (x @ W1^T) )   (needs dinv; independent of fill)
    gemm_kernel<true><<<2048, 256, 0, stream>>>((const float4*)x, W1, dinv, y1, n);

    fill_kernel<<<(E / 4 + 255) / 256, 256, 0, stream>>>(src, dst, rank, rowptr, csr_src, E);

    gather1_kernel<<<2048, 256, 0, stream>>>(
        (const float2*)y1, rowptr, csr_src, dinv, b1, h1s, n);

    // y2 = fp16( h1s @ W2^T )
    gemm_kernel<false><<<2048, 256, 0, stream>>>((const float4*)h1s, W2, nullptr, y2, n);

    gather2_kernel<<<2048, 256, 0, stream>>>(
        (const float2*)y2, rowptr, csr_src, dinv, b2, W3, b3, out, n);
}

// Round 7
// 283.493 us; speedup vs baseline: 2.5252x; 1.0601x over previous
//
#include <hip/hip_runtime.h>
#include <hip/hip_fp16.h>

// SGC forward, GEMM-commuted form with fp16 gather tables, quarter-wave gathers:
//   prop(x) @ W^T == prop(x @ W^T)   (propagation is linear, dinv diagonal)
//   dinv[i] = rsqrt(indeg[i]+1)
//   y1  = fp16( dinv .* (x @ W1^T) )               (dense GEMM, scaled epilogue)
//   h1s = dinv .* relu( dinv[d]*(sum y1[s] + y1[d]) + b1 )   (gather, fp32 accum)
//   y2  = fp16( h1s @ W2^T )                       (dense GEMM)
//   h2  = relu( dinv[d]*(sum y2[s] + y2[d]) + b2 )
//   out = h2 @ W3^T + b3                           (fused in gather2, intra-quarter shfl)
// Gather structure: ONE QUARTER-WAVE PER NODE (lane m = features 4m..4m+3).
// 4 independent edge chains per wave x 8-edge unroll = 32 row-loads in flight
// (round-6 was 1 chain/wave -> latency-bound at 42% occ / 30% VALU).

#define F 64
#define C 16
#define SCAN_B 1024

// load 4 consecutive fp16 features (8B) and widen to float4
__device__ __forceinline__ float4 ld_h4(const float2* base, size_t idx) {
    float2 raw = base[idx];
    __half2 lo = __builtin_bit_cast(__half2, raw.x);
    __half2 hi = __builtin_bit_cast(__half2, raw.y);
    float2 f0 = __half22float2(lo);
    float2 f1 = __half22float2(hi);
    return make_float4(f0.x, f0.y, f1.x, f1.y);
}

__device__ __forceinline__ float rl(float v, int l) {
    return __uint_as_float(__builtin_amdgcn_readlane(__float_as_uint(v), l));
}

// ---- histogram + per-edge rank (one atomic pass) ----
__global__ void degrank_kernel(const int* __restrict__ dst, int* __restrict__ deg,
                               int* __restrict__ rank, int E) {
    int i = (blockIdx.x * blockDim.x + threadIdx.x) * 4;
    if (i + 4 <= E) {
        int4 d = *(const int4*)(dst + i);
        rank[i]     = atomicAdd(&deg[d.x], 1);
        rank[i + 1] = atomicAdd(&deg[d.y], 1);
        rank[i + 2] = atomicAdd(&deg[d.z], 1);
        rank[i + 3] = atomicAdd(&deg[d.w], 1);
    } else {
        for (int k = i; k < E; ++k) rank[k] = atomicAdd(&deg[dst[k]], 1);
    }
}

// ---- exclusive scan of deg -> rowptr ----
__global__ __launch_bounds__(256) void scan1_kernel(const int* __restrict__ deg,
                                                    int* __restrict__ part,
                                                    int* __restrict__ bsum, int n) {
    __shared__ int ts[256];
    int b = blockIdx.x, t = threadIdx.x;
    int base = b * SCAN_B + t * 4;
    int v[4], sum = 0;
#pragma unroll
    for (int k = 0; k < 4; ++k) { int i = base + k; v[k] = (i < n) ? deg[i] : 0; sum += v[k]; }
    ts[t] = sum;
    __syncthreads();
    for (int off = 1; off < 256; off <<= 1) {
        int add = (t >= off) ? ts[t - off] : 0;
        __syncthreads();
        ts[t] += add;
        __syncthreads();
    }
    int run = ts[t] - sum;
#pragma unroll
    for (int k = 0; k < 4; ++k) { int i = base + k; if (i < n) part[i] = run; run += v[k]; }
    if (t == 255) bsum[b] = ts[255];
}

__global__ __launch_bounds__(256) void scan2_kernel(int* __restrict__ bsum, int nb) {
    __shared__ int ts[256];
    int t = threadIdx.x;
    int v = (t < nb) ? bsum[t] : 0;
    ts[t] = v;
    __syncthreads();
    for (int off = 1; off < 256; off <<= 1) {
        int add = (t >= off) ? ts[t - off] : 0;
        __syncthreads();
        ts[t] += add;
        __syncthreads();
    }
    if (t < nb) bsum[t] = ts[t] - v;
}

__global__ void scan3_kernel(const int* __restrict__ part, const int* __restrict__ bsum,
                             const int* __restrict__ deg, int* __restrict__ rowptr,
                             float* __restrict__ dinv, int n, int E) {
    int i = blockIdx.x * blockDim.x + threadIdx.x;
    if (i < n) {
        rowptr[i] = part[i] + bsum[i / SCAN_B];
        dinv[i] = rsqrtf((float)deg[i] + 1.0f);
    }
    if (i == 0) rowptr[n] = E;
}

// ---- atomic-free bucket fill ----
__global__ void fill_kernel(const int* __restrict__ src, const int* __restrict__ dst,
                            const int* __restrict__ rank, const int* __restrict__ rowptr,
                            int* __restrict__ csr_src, int E) {
    int i = (blockIdx.x * blockDim.x + threadIdx.x) * 4;
    if (i + 4 <= E) {
        int4 s = *(const int4*)(src + i);
        int4 d = *(const int4*)(dst + i);
        int4 r = *(const int4*)(rank + i);
        csr_src[rowptr[d.x] + r.x] = s.x;
        csr_src[rowptr[d.y] + r.y] = s.y;
        csr_src[rowptr[d.z] + r.z] = s.z;
        csr_src[rowptr[d.w] + r.w] = s.w;
    } else {
        for (int k = i; k < E; ++k) csr_src[rowptr[dst[k]] + rank[k]] = src[k];
    }
}

// ---- dense GEMM: yout[i][j] = fp16( (in[i] . W[j]) * (SCALE ? scale[i] : 1) ) ----
template <bool SCALE>
__global__ __launch_bounds__(256) void gemm_kernel(
    const float4* __restrict__ in4, const float* __restrict__ W,
    const float* __restrict__ scale, __half* __restrict__ yout, int n) {
    int tid = threadIdx.x;
    int lane = tid & 63;
    int m = lane & 15;
    float4 w[16];
#pragma unroll
    for (int t = 0; t < 16; ++t) w[t] = *(const float4*)(W + (size_t)lane * F + 4 * t);
    int gw = blockIdx.x * 4 + (tid >> 6);
    int nw = gridDim.x * 4;
    int node = gw;
    if (node >= n) return;
    float4 v = in4[(size_t)node * 16 + m];
    while (true) {
        int nxt = node + nw;
        float4 vn;
        if (nxt < n) vn = in4[(size_t)nxt * 16 + m];   // prefetch next row
        float acc = 0.0f;
#pragma unroll
        for (int t = 0; t < 16; ++t) {
            acc = fmaf(rl(v.x, t), w[t].x, acc);
            acc = fmaf(rl(v.y, t), w[t].y, acc);
            acc = fmaf(rl(v.z, t), w[t].z, acc);
            acc = fmaf(rl(v.w, t), w[t].w, acc);
        }
        if (SCALE) acc *= scale[node];
        yout[(size_t)node * F + lane] = __float2half(acc);
        if (nxt >= n) break;
        v = vn;
        node = nxt;
    }
}

// ---- gather1: quarter-wave per node; pure-add fp16 gather -> h1s (fp32) ----
__global__ __launch_bounds__(256) void gather1_kernel(
    const float2* __restrict__ y, const int* __restrict__ rowptr,
    const int* __restrict__ csr_src, const float* __restrict__ dinv,
    const float* __restrict__ b1, float* __restrict__ h1s, int n) {
    int tid = threadIdx.x;
    int m = tid & 15;
    float4 bias = *(const float4*)(b1 + 4 * m);
    int qid = (blockIdx.x * 256 + tid) >> 4;   // global quarter id
    int nq = (gridDim.x * 256) >> 4;
    for (int node = qid; node < n; node += nq) {
        int beg = rowptr[node], end = rowptr[node + 1];
        float4 a0 = {0, 0, 0, 0}, a1 = {0, 0, 0, 0}, a2 = {0, 0, 0, 0}, a3 = {0, 0, 0, 0};
        int p = beg;
        for (; p + 8 <= end; p += 8) {
            int s0 = csr_src[p],     s1 = csr_src[p + 1];
            int s2 = csr_src[p + 2], s3 = csr_src[p + 3];
            int s4 = csr_src[p + 4], s5 = csr_src[p + 5];
            int s6 = csr_src[p + 6], s7 = csr_src[p + 7];
            float4 v0 = ld_h4(y, (size_t)s0 * 16 + m);
            float4 v1 = ld_h4(y, (size_t)s1 * 16 + m);
            float4 v2 = ld_h4(y, (size_t)s2 * 16 + m);
            float4 v3 = ld_h4(y, (size_t)s3 * 16 + m);
            float4 v4 = ld_h4(y, (size_t)s4 * 16 + m);
            float4 v5 = ld_h4(y, (size_t)s5 * 16 + m);
            float4 v6 = ld_h4(y, (size_t)s6 * 16 + m);
            float4 v7 = ld_h4(y, (size_t)s7 * 16 + m);
            a0.x += v0.x + v4.x; a0.y += v0.y + v4.y; a0.z += v0.z + v4.z; a0.w += v0.w + v4.w;
            a1.x += v1.x + v5.x; a1.y += v1.y + v5.y; a1.z += v1.z + v5.z; a1.w += v1.w + v5.w;
            a2.x += v2.x + v6.x; a2.y += v2.y + v6.y; a2.z += v2.z + v6.z; a2.w += v2.w + v6.w;
            a3.x += v3.x + v7.x; a3.y += v3.y + v7.y; a3.z += v3.z + v7.z; a3.w += v3.w + v7.w;
        }
        if (p + 4 <= end) {
            int s0 = csr_src[p], s1 = csr_src[p + 1], s2 = csr_src[p + 2], s3 = csr_src[p + 3];
            float4 v0 = ld_h4(y, (size_t)s0 * 16 + m);
            float4 v1 = ld_h4(y, (size_t)s1 * 16 + m);
            float4 v2 = ld_h4(y, (size_t)s2 * 16 + m);
            float4 v3 = ld_h4(y, (size_t)s3 * 16 + m);
            a0.x += v0.x; a0.y += v0.y; a0.z += v0.z; a0.w += v0.w;
            a1.x += v1.x; a1.y += v1.y; a1.z += v1.z; a1.w += v1.w;
            a2.x += v2.x; a2.y += v2.y; a2.z += v2.z; a2.w += v2.w;
            a3.x += v3.x; a3.y += v3.y; a3.z += v3.z; a3.w += v3.w;
            p += 4;
        }
        for (; p < end; ++p) {
            int s = csr_src[p];
            float4 v = ld_h4(y, (size_t)s * 16 + m);
            a0.x += v.x; a0.y += v.y; a0.z += v.z; a0.w += v.w;
        }
        a0.x += a1.x + a2.x + a3.x;
        a0.y += a1.y + a2.y + a3.y;
        a0.z += a1.z + a2.z + a3.z;
        a0.w += a1.w + a2.w + a3.w;
        float dd = dinv[node];
        float4 self = ld_h4(y, (size_t)node * 16 + m);
        float4 r;
        r.x = dd * fmaxf(fmaf(dd, a0.x + self.x, bias.x), 0.0f);
        r.y = dd * fmaxf(fmaf(dd, a0.y + self.y, bias.y), 0.0f);
        r.z = dd * fmaxf(fmaf(dd, a0.z + self.z, bias.z), 0.0f);
        r.w = dd * fmaxf(fmaf(dd, a0.w + self.w, bias.w), 0.0f);
        *(float4*)(h1s + (size_t)node * F + 4 * m) = r;
    }
}

// ---- gather2: quarter-wave per node; gather + lin2 + relu + W3 (intra-quarter shfl) ----
__global__ __launch_bounds__(256) void gather2_kernel(
    const float2* __restrict__ y, const int* __restrict__ rowptr,
    const int* __restrict__ csr_src, const float* __restrict__ dinv,
    const float* __restrict__ b2, const float* __restrict__ W3,
    const float* __restrict__ b3, float* __restrict__ out, int n) {
    int tid = threadIdx.x;
    int lane = tid & 63;
    int m = lane & 15;
    int qbase = lane & 48;
    float4 bias = *(const float4*)(b2 + 4 * m);
    float b3r = b3[m];
    int qid = (blockIdx.x * 256 + tid) >> 4;
    int nq = (gridDim.x * 256) >> 4;
    for (int node = qid; node < n; node += nq) {
        int beg = rowptr[node], end = rowptr[node + 1];
        float4 a0 = {0, 0, 0, 0}, a1 = {0, 0, 0, 0}, a2 = {0, 0, 0, 0}, a3 = {0, 0, 0, 0};
        int p = beg;
        for (; p + 8 <= end; p += 8) {
            int s0 = csr_src[p],     s1 = csr_src[p + 1];
            int s2 = csr_src[p + 2], s3 = csr_src[p + 3];
            int s4 = csr_src[p + 4], s5 = csr_src[p + 5];
            int s6 = csr_src[p + 6], s7 = csr_src[p + 7];
            float4 v0 = ld_h4(y, (size_t)s0 * 16 + m);
            float4 v1 = ld_h4(y, (size_t)s1 * 16 + m);
            float4 v2 = ld_h4(y, (size_t)s2 * 16 + m);
            float4 v3 = ld_h4(y, (size_t)s3 * 16 + m);
            float4 v4 = ld_h4(y, (size_t)s4 * 16 + m);
            float4 v5 = ld_h4(y, (size_t)s5 * 16 + m);
            float4 v6 = ld_h4(y, (size_t)s6 * 16 + m);
            float4 v7 = ld_h4(y, (size_t)s7 * 16 + m);
            a0.x += v0.x + v4.x; a0.y += v0.y + v4.y; a0.z += v0.z + v4.z; a0.w += v0.w + v4.w;
            a1.x += v1.x + v5.x; a1.y += v1.y + v5.y; a1.z += v1.z + v5.z; a1.w += v1.w + v5.w;
            a2.x += v2.x + v6.x; a2.y += v2.y + v6.y; a2.z += v2.z + v6.z; a2.w += v2.w + v6.w;
            a3.x += v3.x + v7.x; a3.y += v3.y + v7.y; a3.z += v3.z + v7.z; a3.w += v3.w + v7.w;
        }
        if (p + 4 <= end) {
            int s0 = csr_src[p], s1 = csr_src[p + 1], s2 = csr_src[p + 2], s3 = csr_src[p + 3];
            float4 v0 = ld_h4(y, (size_t)s0 * 16 + m);
            float4 v1 = ld_h4(y, (size_t)s1 * 16 + m);
            float4 v2 = ld_h4(y, (size_t)s2 * 16 + m);
            float4 v3 = ld_h4(y, (size_t)s3 * 16 + m);
            a0.x += v0.x; a0.y += v0.y; a0.z += v0.z; a0.w += v0.w;
            a1.x += v1.x; a1.y += v1.y; a1.z += v1.z; a1.w += v1.w;
            a2.x += v2.x; a2.y += v2.y; a2.z += v2.z; a2.w += v2.w;
            a3.x += v3.x; a3.y += v3.y; a3.z += v3.z; a3.w += v3.w;
            p += 4;
        }
        for (; p < end; ++p) {
            int s = csr_src[p];
            float4 v = ld_h4(y, (size_t)s * 16 + m);
            a0.x += v.x; a0.y += v.y; a0.z += v.z; a0.w += v.w;
        }
        a0.x += a1.x + a2.x + a3.x;
        a0.y += a1.y + a2.y + a3.y;
        a0.z += a1.z + a2.z + a3.z;
        a0.w += a1.w + a2.w + a3.w;
        float dd = dinv[node];
        float4 self = ld_h4(y, (size_t)node * 16 + m);
        float4 h;   // lane m of quarter: h2 features [4m..4m+3]
        h.x = fmaxf(fmaf(dd, a0.x + self.x, bias.x), 0.0f);
        h.y = fmaxf(fmaf(dd, a0.y + self.y, bias.y), 0.0f);
        h.z = fmaxf(fmaf(dd, a0.z + self.z, bias.z), 0.0f);
        h.w = fmaxf(fmaf(dd, a0.w + self.w, bias.w), 0.0f);
        // out[node][m] = b3[m] + sum_t dot(h2[4t..4t+3], W3[m][4t..4t+3])
        float acc = 0.0f;
#pragma unroll
        for (int t = 0; t < 16; ++t) {
            float4 wv = *(const float4*)(W3 + (size_t)m * F + 4 * t);   // L1-hot
            float hx = __shfl(h.x, qbase + t);
            float hy = __shfl(h.y, qbase + t);
            float hz = __shfl(h.z, qbase + t);
            float hw = __shfl(h.w, qbase + t);
            acc = fmaf(hx, wv.x, fmaf(hy, wv.y, fmaf(hz, wv.z, fmaf(hw, wv.w, acc))));
        }
        out[(size_t)node * C + m] = acc + b3r;
    }
}

extern "C" void kernel_launch(void* const* d_in, const int* in_sizes, int n_in,
                              void* d_out, int out_size, void* d_ws, size_t ws_size,
                              hipStream_t stream) {
    const float* x  = (const float*)d_in[0];
    const int* edge = (const int*)d_in[1];
    const float* W1 = (const float*)d_in[2];
    const float* b1 = (const float*)d_in[3];
    const float* W2 = (const float*)d_in[4];
    const float* b2 = (const float*)d_in[5];
    const float* W3 = (const float*)d_in[6];
    const float* b3 = (const float*)d_in[7];
    float* out = (float*)d_out;

    int n = in_sizes[0] / F;        // 100000
    int E = in_sizes[1] / 2;        // 1600000
    const int* src = edge;
    const int* dst = edge + E;

    int nb = (n + SCAN_B - 1) / SCAN_B;

    char* ws = (char*)d_ws;
    size_t o = 0;
    auto alloc = [&](size_t bytes) { char* p = ws + o; o += (bytes + 255) & ~(size_t)255; return p; };
    int*    deg     = (int*)   alloc((size_t)n * 4);
    int*    rank    = (int*)   alloc((size_t)E * 4);
    int*    part    = (int*)   alloc((size_t)n * 4);
    int*    bsum    = (int*)   alloc(256 * 4);
    int*    rowptr  = (int*)   alloc((size_t)(n + 1) * 4);
    int*    csr_src = (int*)   alloc((size_t)E * 4);
    float*  dinv    = (float*) alloc((size_t)n * 4);
    __half* y1      = (__half*)alloc((size_t)n * F * 2);   // reused as y2
    float*  h1s     = (float*) alloc((size_t)n * F * 4);
    __half* y2      = y1;                                   // y1 dead after gather1

    hipMemsetAsync(deg, 0, (size_t)n * 4, stream);
    degrank_kernel<<<(E / 4 + 255) / 256, 256, 0, stream>>>(dst, deg, rank, E);

    scan1_kernel<<<nb, 256, 0, stream>>>(deg, part, bsum, n);
    scan2_kernel<<<1, 256, 0, stream>>>(bsum, nb);
    scan3_kernel<<<(n + 255) / 256, 256, 0, stream>>>(part, bsum, deg, rowptr, dinv, n, E);

    // y1 = fp16( dinv .* (x @ W1^T) )   (needs dinv; independent of fill)
    gemm_kernel<true><<<2048, 256, 0, stream>>>((const float4*)x, W1, dinv, y1, n);

    fill_kernel<<<(E / 4 + 255) / 256, 256, 0, stream>>>(src, dst, rank, rowptr, csr_src, E);

    gather1_kernel<<<2048, 256, 0, stream>>>(
        (const float2*)y1, rowptr, csr_src, dinv, b1, h1s, n);

    // y2 = fp16( h1s @ W2^T )
    gemm_kernel<false><<<2048, 256, 0, stream>>>((const float4*)h1s, W2, nullptr, y2, n);

    gather2_kernel<<<2048, 256, 0, stream>>>(
        (const float2*)y2, rowptr, csr_src, dinv, b2, W3, b3, out, n);
}

// Round 8
// 269.565 us; speedup vs baseline: 2.6557x; 1.0517x over previous
//
#include <hip/hip_runtime.h>
#include <hip/hip_fp16.h>

// SGC forward, GEMM-commuted both directions, fp16 gather tables:
//   prop(x) @ W^T == prop(x @ W^T)        (propagation linear, dinv diagonal)
//   dinv[i] = rsqrt(indeg[i]+1)
//   y1  = fp16( dinv .* (x @ W1^T) )                  (dense GEMM, scaled epilogue)
//   h1s = fp16( dinv .* relu( dinv[d]*(sum y1[s] + y1[d]) + b1 ) )   (gather1)
//   out = relu( [dinv[d]*(sum h1s[s] + h1s[d])] @ W2^T + b2 ) @ W3^T + b3
//         ^-- gather2 gathers h1s directly; W2+W3 applied in-register per node.
// gemm2/y2 eliminated. Gather floor = per-XCD L2 miss rate (~1.2 TB/s fill):
// FETCH ~= 8 XCDs x table size (compulsory), so fp16 tables are the lever.

#define F 64
#define C 16
#define SCAN_B 1024

__device__ __forceinline__ float rl(float v, int l) {
    return __uint_as_float(__builtin_amdgcn_readlane(__float_as_uint(v), l));
}

// load 4 consecutive fp16 features (8B) and widen to float4
__device__ __forceinline__ float4 ld_h4(const float2* base, size_t idx) {
    float2 raw = base[idx];
    __half2 lo = __builtin_bit_cast(__half2, raw.x);
    __half2 hi = __builtin_bit_cast(__half2, raw.y);
    float2 f0 = __half22float2(lo);
    float2 f1 = __half22float2(hi);
    return make_float4(f0.x, f0.y, f1.x, f1.y);
}

// ---- histogram + per-edge rank (one atomic pass) ----
__global__ void degrank_kernel(const int* __restrict__ dst, int* __restrict__ deg,
                               int* __restrict__ rank, int E) {
    int i = (blockIdx.x * blockDim.x + threadIdx.x) * 4;
    if (i + 4 <= E) {
        int4 d = *(const int4*)(dst + i);
        rank[i]     = atomicAdd(&deg[d.x], 1);
        rank[i + 1] = atomicAdd(&deg[d.y], 1);
        rank[i + 2] = atomicAdd(&deg[d.z], 1);
        rank[i + 3] = atomicAdd(&deg[d.w], 1);
    } else {
        for (int k = i; k < E; ++k) rank[k] = atomicAdd(&deg[dst[k]], 1);
    }
}

// ---- exclusive scan of deg -> rowptr ----
__global__ __launch_bounds__(256) void scan1_kernel(const int* __restrict__ deg,
                                                    int* __restrict__ part,
                                                    int* __restrict__ bsum, int n) {
    __shared__ int ts[256];
    int b = blockIdx.x, t = threadIdx.x;
    int base = b * SCAN_B + t * 4;
    int v[4], sum = 0;
#pragma unroll
    for (int k = 0; k < 4; ++k) { int i = base + k; v[k] = (i < n) ? deg[i] : 0; sum += v[k]; }
    ts[t] = sum;
    __syncthreads();
    for (int off = 1; off < 256; off <<= 1) {
        int add = (t >= off) ? ts[t - off] : 0;
        __syncthreads();
        ts[t] += add;
        __syncthreads();
    }
    int run = ts[t] - sum;
#pragma unroll
    for (int k = 0; k < 4; ++k) { int i = base + k; if (i < n) part[i] = run; run += v[k]; }
    if (t == 255) bsum[b] = ts[255];
}

__global__ __launch_bounds__(256) void scan2_kernel(int* __restrict__ bsum, int nb) {
    __shared__ int ts[256];
    int t = threadIdx.x;
    int v = (t < nb) ? bsum[t] : 0;
    ts[t] = v;
    __syncthreads();
    for (int off = 1; off < 256; off <<= 1) {
        int add = (t >= off) ? ts[t - off] : 0;
        __syncthreads();
        ts[t] += add;
        __syncthreads();
    }
    if (t < nb) bsum[t] = ts[t] - v;
}

__global__ void scan3_kernel(const int* __restrict__ part, const int* __restrict__ bsum,
                             const int* __restrict__ deg, int* __restrict__ rowptr,
                             float* __restrict__ dinv, int n, int E) {
    int i = blockIdx.x * blockDim.x + threadIdx.x;
    if (i < n) {
        rowptr[i] = part[i] + bsum[i / SCAN_B];
        dinv[i] = rsqrtf((float)deg[i] + 1.0f);
    }
    if (i == 0) rowptr[n] = E;
}

// ---- atomic-free bucket fill ----
__global__ void fill_kernel(const int* __restrict__ src, const int* __restrict__ dst,
                            const int* __restrict__ rank, const int* __restrict__ rowptr,
                            int* __restrict__ csr_src, int E) {
    int i = (blockIdx.x * blockDim.x + threadIdx.x) * 4;
    if (i + 4 <= E) {
        int4 s = *(const int4*)(src + i);
        int4 d = *(const int4*)(dst + i);
        int4 r = *(const int4*)(rank + i);
        csr_src[rowptr[d.x] + r.x] = s.x;
        csr_src[rowptr[d.y] + r.y] = s.y;
        csr_src[rowptr[d.z] + r.z] = s.z;
        csr_src[rowptr[d.w] + r.w] = s.w;
    } else {
        for (int k = i; k < E; ++k) csr_src[rowptr[dst[k]] + rank[k]] = src[k];
    }
}

// ---- dense GEMM: y1[i][j] = fp16( scale[i] * (in[i] . W1[j]) ) ----
__global__ __launch_bounds__(256) void gemm1_kernel(
    const float4* __restrict__ in4, const float* __restrict__ W,
    const float* __restrict__ scale, __half* __restrict__ yout, int n) {
    int tid = threadIdx.x;
    int lane = tid & 63;
    int m = lane & 15;
    float4 w[16];
#pragma unroll
    for (int t = 0; t < 16; ++t) w[t] = *(const float4*)(W + (size_t)lane * F + 4 * t);
    int gw = blockIdx.x * 4 + (tid >> 6);
    int nw = gridDim.x * 4;
    int node = gw;
    if (node >= n) return;
    float4 v = in4[(size_t)node * 16 + m];
    while (true) {
        int nxt = node + nw;
        float4 vn;
        if (nxt < n) vn = in4[(size_t)nxt * 16 + m];   // prefetch next row
        float acc = 0.0f;
#pragma unroll
        for (int t = 0; t < 16; ++t) {
            acc = fmaf(rl(v.x, t), w[t].x, acc);
            acc = fmaf(rl(v.y, t), w[t].y, acc);
            acc = fmaf(rl(v.z, t), w[t].z, acc);
            acc = fmaf(rl(v.w, t), w[t].w, acc);
        }
        acc *= scale[node];
        yout[(size_t)node * F + lane] = __float2half(acc);
        if (nxt >= n) break;
        v = vn;
        node = nxt;
    }
}

// ---- gather1: quarter-wave per node; pure-add fp16 gather -> h1s (fp16) ----
__global__ __launch_bounds__(256) void gather1_kernel(
    const float2* __restrict__ y, const int* __restrict__ rowptr,
    const int* __restrict__ csr_src, const float* __restrict__ dinv,
    const float* __restrict__ b1, __half* __restrict__ h1s, int n) {
    int tid = threadIdx.x;
    int m = tid & 15;
    float4 bias = *(const float4*)(b1 + 4 * m);
    int qid = (blockIdx.x * 256 + tid) >> 4;   // global quarter id
    int nq = (gridDim.x * 256) >> 4;
    for (int node = qid; node < n; node += nq) {
        int beg = rowptr[node], end = rowptr[node + 1];
        float4 a0 = {0, 0, 0, 0}, a1 = {0, 0, 0, 0}, a2 = {0, 0, 0, 0}, a3 = {0, 0, 0, 0};
        int p = beg;
        for (; p + 8 <= end; p += 8) {
            int s0 = csr_src[p],     s1 = csr_src[p + 1];
            int s2 = csr_src[p + 2], s3 = csr_src[p + 3];
            int s4 = csr_src[p + 4], s5 = csr_src[p + 5];
            int s6 = csr_src[p + 6], s7 = csr_src[p + 7];
            float4 v0 = ld_h4(y, (size_t)s0 * 16 + m);
            float4 v1 = ld_h4(y, (size_t)s1 * 16 + m);
            float4 v2 = ld_h4(y, (size_t)s2 * 16 + m);
            float4 v3 = ld_h4(y, (size_t)s3 * 16 + m);
            float4 v4 = ld_h4(y, (size_t)s4 * 16 + m);
            float4 v5 = ld_h4(y, (size_t)s5 * 16 + m);
            float4 v6 = ld_h4(y, (size_t)s6 * 16 + m);
            float4 v7 = ld_h4(y, (size_t)s7 * 16 + m);
            a0.x += v0.x + v4.x; a0.y += v0.y + v4.y; a0.z += v0.z + v4.z; a0.w += v0.w + v4.w;
            a1.x += v1.x + v5.x; a1.y += v1.y + v5.y; a1.z += v1.z + v5.z; a1.w += v1.w + v5.w;
            a2.x += v2.x + v6.x; a2.y += v2.y + v6.y; a2.z += v2.z + v6.z; a2.w += v2.w + v6.w;
            a3.x += v3.x + v7.x; a3.y += v3.y + v7.y; a3.z += v3.z + v7.z; a3.w += v3.w + v7.w;
        }
        if (p + 4 <= end) {
            int s0 = csr_src[p], s1 = csr_src[p + 1], s2 = csr_src[p + 2], s3 = csr_src[p + 3];
            float4 v0 = ld_h4(y, (size_t)s0 * 16 + m);
            float4 v1 = ld_h4(y, (size_t)s1 * 16 + m);
            float4 v2 = ld_h4(y, (size_t)s2 * 16 + m);
            float4 v3 = ld_h4(y, (size_t)s3 * 16 + m);
            a0.x += v0.x; a0.y += v0.y; a0.z += v0.z; a0.w += v0.w;
            a1.x += v1.x; a1.y += v1.y; a1.z += v1.z; a1.w += v1.w;
            a2.x += v2.x; a2.y += v2.y; a2.z += v2.z; a2.w += v2.w;
            a3.x += v3.x; a3.y += v3.y; a3.z += v3.z; a3.w += v3.w;
            p += 4;
        }
        for (; p < end; ++p) {
            int s = csr_src[p];
            float4 v = ld_h4(y, (size_t)s * 16 + m);
            a0.x += v.x; a0.y += v.y; a0.z += v.z; a0.w += v.w;
        }
        a0.x += a1.x + a2.x + a3.x;
        a0.y += a1.y + a2.y + a3.y;
        a0.z += a1.z + a2.z + a3.z;
        a0.w += a1.w + a2.w + a3.w;
        float dd = dinv[node];
        float4 self = ld_h4(y, (size_t)node * 16 + m);
        float4 r;
        r.x = dd * fmaxf(fmaf(dd, a0.x + self.x, bias.x), 0.0f);
        r.y = dd * fmaxf(fmaf(dd, a0.y + self.y, bias.y), 0.0f);
        r.z = dd * fmaxf(fmaf(dd, a0.z + self.z, bias.z), 0.0f);
        r.w = dd * fmaxf(fmaf(dd, a0.w + self.w, bias.w), 0.0f);
        __half2 lo = __float22half2_rn(make_float2(r.x, r.y));
        __half2 hi = __float22half2_rn(make_float2(r.z, r.w));
        float2 packed;
        packed.x = __builtin_bit_cast(float, lo);
        packed.y = __builtin_bit_cast(float, hi);
        *(float2*)(h1s + (size_t)node * F + 4 * m) = packed;   // 8B store, 128B/node
    }
}

// ---- gather2: quarter-wave gather of h1s + per-node W2 (readlane) + relu + W3 (shfl) ----
__global__ __launch_bounds__(256) void gather2_kernel(
    const float2* __restrict__ y, const int* __restrict__ rowptr,
    const int* __restrict__ csr_src, const float* __restrict__ dinv,
    const float* __restrict__ W2, const float* __restrict__ b2,
    const float* __restrict__ W3, const float* __restrict__ b3,
    float* __restrict__ out, int n) {
    int tid = threadIdx.x;
    int lane = tid & 63;
    int q = lane >> 4, m = lane & 15;
    int qbase = lane & 48;
    float4 w2[16];   // W2[lane][4t..4t+3] — register tile, loaded once
#pragma unroll
    for (int t = 0; t < 16; ++t) w2[t] = *(const float4*)(W2 + (size_t)lane * F + 4 * t);
    float4 w3[4];    // W3[m][16q+4t..+3]
#pragma unroll
    for (int t = 0; t < 4; ++t) w3[t] = *(const float4*)(W3 + (size_t)m * F + 16 * q + 4 * t);
    float b2r = b2[lane];
    float b3v = b3[m];
    int wid = (blockIdx.x * 256 + tid) >> 6;
    int nwaves = (gridDim.x * 256) >> 6;
    for (int nb = wid * 4; nb < n; nb += nwaves * 4) {   // wave-uniform loop
        int node = nb + q;                               // this quarter's node
        bool act = node < n;
        int beg = 0, end = 0;
        float dd = 0.0f;
        if (act) { beg = rowptr[node]; end = rowptr[node + 1]; dd = dinv[node]; }
        float4 a0 = {0, 0, 0, 0}, a1 = {0, 0, 0, 0}, a2 = {0, 0, 0, 0}, a3 = {0, 0, 0, 0};
        int p = beg;
        for (; p + 8 <= end; p += 8) {
            int s0 = csr_src[p],     s1 = csr_src[p + 1];
            int s2 = csr_src[p + 2], s3 = csr_src[p + 3];
            int s4 = csr_src[p + 4], s5 = csr_src[p + 5];
            int s6 = csr_src[p + 6], s7 = csr_src[p + 7];
            float4 v0 = ld_h4(y, (size_t)s0 * 16 + m);
            float4 v1 = ld_h4(y, (size_t)s1 * 16 + m);
            float4 v2 = ld_h4(y, (size_t)s2 * 16 + m);
            float4 v3 = ld_h4(y, (size_t)s3 * 16 + m);
            float4 v4 = ld_h4(y, (size_t)s4 * 16 + m);
            float4 v5 = ld_h4(y, (size_t)s5 * 16 + m);
            float4 v6 = ld_h4(y, (size_t)s6 * 16 + m);
            float4 v7 = ld_h4(y, (size_t)s7 * 16 + m);
            a0.x += v0.x + v4.x; a0.y += v0.y + v4.y; a0.z += v0.z + v4.z; a0.w += v0.w + v4.w;
            a1.x += v1.x + v5.x; a1.y += v1.y + v5.y; a1.z += v1.z + v5.z; a1.w += v1.w + v5.w;
            a2.x += v2.x + v6.x; a2.y += v2.y + v6.y; a2.z += v2.z + v6.z; a2.w += v2.w + v6.w;
            a3.x += v3.x + v7.x; a3.y += v3.y + v7.y; a3.z += v3.z + v7.z; a3.w += v3.w + v7.w;
        }
        if (p + 4 <= end) {
            int s0 = csr_src[p], s1 = csr_src[p + 1], s2 = csr_src[p + 2], s3 = csr_src[p + 3];
            float4 v0 = ld_h4(y, (size_t)s0 * 16 + m);
            float4 v1 = ld_h4(y, (size_t)s1 * 16 + m);
            float4 v2 = ld_h4(y, (size_t)s2 * 16 + m);
            float4 v3 = ld_h4(y, (size_t)s3 * 16 + m);
            a0.x += v0.x; a0.y += v0.y; a0.z += v0.z; a0.w += v0.w;
            a1.x += v1.x; a1.y += v1.y; a1.z += v1.z; a1.w += v1.w;
            a2.x += v2.x; a2.y += v2.y; a2.z += v2.z; a2.w += v2.w;
            a3.x += v3.x; a3.y += v3.y; a3.z += v3.z; a3.w += v3.w;
            p += 4;
        }
        for (; p < end; ++p) {
            int s = csr_src[p];
            float4 v = ld_h4(y, (size_t)s * 16 + m);
            a0.x += v.x; a0.y += v.y; a0.z += v.z; a0.w += v.w;
        }
        a0.x += a1.x + a2.x + a3.x;
        a0.y += a1.y + a2.y + a3.y;
        a0.z += a1.z + a2.z + a3.z;
        a0.w += a1.w + a2.w + a3.w;
        float4 t4 = {0, 0, 0, 0};   // propagated vector, features 4m..4m+3 of node
        if (act) {
            float4 self = ld_h4(y, (size_t)node * 16 + m);
            t4.x = dd * (a0.x + self.x);
            t4.y = dd * (a0.y + self.y);
            t4.z = dd * (a0.z + self.z);
            t4.w = dd * (a0.w + self.w);
        }
        // Epilogue: per node qq (wave-cooperative): z2 = t @ W2^T + b2 (readlane,
        // uniform lane index), h2 = relu(z2) on lane j, out = h2 @ W3^T + b3 (shfl).
#pragma unroll
        for (int qq = 0; qq < 4; ++qq) {
            if (nb + qq >= n) break;   // wave-uniform
            float z = b2r;
#pragma unroll
            for (int tt = 0; tt < 16; ++tt) {
                z = fmaf(rl(t4.x, 16 * qq + tt), w2[tt].x, z);
                z = fmaf(rl(t4.y, 16 * qq + tt), w2[tt].y, z);
                z = fmaf(rl(t4.z, 16 * qq + tt), w2[tt].z, z);
                z = fmaf(rl(t4.w, 16 * qq + tt), w2[tt].w, z);
            }
            float h2 = fmaxf(z, 0.0f);           // lane j holds h2[j]
            const float* w3f = (const float*)w3;
            float partial = 0.0f;
#pragma unroll
            for (int tt = 0; tt < 16; ++tt)
                partial = fmaf(__shfl(h2, qbase + tt), w3f[tt], partial);
            partial += __shfl_xor(partial, 16);
            partial += __shfl_xor(partial, 32);
            if (lane < 16) out[(size_t)(nb + qq) * C + lane] = partial + b3v;
        }
    }
}

extern "C" void kernel_launch(void* const* d_in, const int* in_sizes, int n_in,
                              void* d_out, int out_size, void* d_ws, size_t ws_size,
                              hipStream_t stream) {
    const float* x  = (const float*)d_in[0];
    const int* edge = (const int*)d_in[1];
    const float* W1 = (const float*)d_in[2];
    const float* b1 = (const float*)d_in[3];
    const float* W2 = (const float*)d_in[4];
    const float* b2 = (const float*)d_in[5];
    const float* W3 = (const float*)d_in[6];
    const float* b3 = (const float*)d_in[7];
    float* out = (float*)d_out;

    int n = in_sizes[0] / F;        // 100000
    int E = in_sizes[1] / 2;        // 1600000
    const int* src = edge;
    const int* dst = edge + E;

    int nb = (n + SCAN_B - 1) / SCAN_B;

    char* ws = (char*)d_ws;
    size_t o = 0;
    auto alloc = [&](size_t bytes) { char* p = ws + o; o += (bytes + 255) & ~(size_t)255; return p; };
    int*    deg     = (int*)   alloc((size_t)n * 4);
    int*    rank    = (int*)   alloc((size_t)E * 4);
    int*    part    = (int*)   alloc((size_t)n * 4);
    int*    bsum    = (int*)   alloc(256 * 4);
    int*    rowptr  = (int*)   alloc((size_t)(n + 1) * 4);
    int*    csr_src = (int*)   alloc((size_t)E * 4);
    float*  dinv    = (float*) alloc((size_t)n * 4);
    __half* y1      = (__half*)alloc((size_t)n * F * 2);
    __half* h1s     = (__half*)alloc((size_t)n * F * 2);

    hipMemsetAsync(deg, 0, (size_t)n * 4, stream);
    degrank_kernel<<<(E / 4 + 255) / 256, 256, 0, stream>>>(dst, deg, rank, E);

    scan1_kernel<<<nb, 256, 0, stream>>>(deg, part, bsum, n);
    scan2_kernel<<<1, 256, 0, stream>>>(bsum, nb);
    scan3_kernel<<<(n + 255) / 256, 256, 0, stream>>>(part, bsum, deg, rowptr, dinv, n, E);

    // y1 = fp16( dinv .* (x @ W1^T) )
    gemm1_kernel<<<2048, 256, 0, stream>>>((const float4*)x, W1, dinv, y1, n);

    fill_kernel<<<(E / 4 + 255) / 256, 256, 0, stream>>>(src, dst, rank, rowptr, csr_src, E);

    gather1_kernel<<<2048, 256, 0, stream>>>(
        (const float2*)y1, rowptr, csr_src, dinv, b1, h1s, n);

    gather2_kernel<<<2048, 256, 0, stream>>>(
        (const float2*)h1s, rowptr, csr_src, dinv, W2, b2, W3, b3, out, n);
}